// Round 8
// baseline (329.916 us; speedup 1.0000x reference)
//
#include <hip/hip_runtime.h>
#include <math.h>

#define D 64
#define K 512
#define BLOCK 1024
#define ROWS 256
#define WAVES (BLOCK / 64)
#define NPART 32

typedef __attribute__((ext_vector_type(8))) short bf16x8;
typedef __attribute__((ext_vector_type(4))) float f32x4;

// Bit-level emulation of the harness's numpy fp32 reference (validated at
// absmax 0.0 in R0-R6):
//   dist[i,k] = fp32( fp32(sx[i] + se[k]) - 2*dot[i,k] )
// sx/se = numpy pairwise sums (8-acc kernel, contraction OFF), dot =
// sequential single-accumulator fmaf chain j=0..63 ascending. argmin
// strict-<, first occurrence.
//
// R6 validated the bf16-MFMA screen end-to-end (absmax 0.0) but ran 235us
// with all pipes idle: divergent per-lane row gathers (se/sx prologue,
// epilogue) serialize ~20K cache lines/CU through L1, and 2 waves/SIMD
// hide nothing. R7 keeps the screen bit-identical and fixes only that:
//  - exact np sums via 8-lanes-per-row (lane m owns accumulator r[m];
//    shfl_xor 1/2/4 tree reproduces the exact pairwise bracketing),
//    loads coalesced 32B-contiguous.
//  - epilogue: 4 threads/row coalesced gather/q-write, dx staged to LDS
//    (overlaying dead bf16 tiles), per-row loss chain unchanged.
//  - BLOCK=1024: 16 waves (4/SIMD), one 16-row MFMA tile per wave.
// (R7 bench was an infra flake — container failed to acquire; resubmitted
// unchanged for its first real measurement.)

__device__ __forceinline__ ushort f2bf(float v) {     // RTNE f32->bf16
    unsigned u = __float_as_uint(v);
    return (ushort)((u + 0x7FFFu + ((u >> 16) & 1u)) >> 16);
}
__device__ __forceinline__ float bf2f(ushort h) {
    return __uint_as_float((unsigned)h << 16);
}

// Exact reference dist for one (row,k); lexicographic merge into best_s.
__device__ __noinline__ void exact_merge(
    const float* __restrict__ x, const float* __restrict__ emb,
    int rowg, int code, float sx, float se, unsigned long long* bp)
{
    const float4* xp = (const float4*)(x + (size_t)rowg * D);
    const float4* ep = (const float4*)(emb + (size_t)code * D);
    float a = 0.f;
#pragma unroll
    for (int j = 0; j < 16; ++j) {
        float4 xv = xp[j], ev = ep[j];
        a = fmaf(xv.x, ev.x, a);
        a = fmaf(xv.y, ev.y, a);
        a = fmaf(xv.z, ev.z, a);
        a = fmaf(xv.w, ev.w, a);
    }
    float dd = (sx + se) - 2.0f * a;        // ref rounding (2*a exact)
    unsigned long long key =
        ((unsigned long long)__float_as_uint(dd) << 32) | (unsigned)code;
    atomicMin(bp, key);                      // dist>0 -> bits monotone
}

__global__ __launch_bounds__(BLOCK, 4) void vq_fused(
    const float* __restrict__ x, const float* __restrict__ emb,
    float* __restrict__ q_out, float* __restrict__ idx_out,
    float* __restrict__ block_sums, int* __restrict__ part_hist,
    int* __restrict__ done_ctr,
    float* __restrict__ out_loss, float* __restrict__ out_perp,
    float inv_nelem, float inv_rows)
{
    // 96 KB region: bf16 tiles during the scan; f32 dx rows in the epilogue.
    __shared__ float4 bigs[6144];
    ushort* ebf = (ushort*)bigs;                 // [K*D]    64 KB
    ushort* xbf = ((ushort*)bigs) + K * D;       // [ROWS*D] 32 KB
    float*  dxs = (float*)bigs;                  // [ROWS][68] overlay, 69.6 KB

    __shared__ float se_s[K];                    // exact ||e||^2 (numpy)
    __shared__ float sx_s[ROWS];                 // exact ||x||^2 (numpy)
    __shared__ float epre_s[ROWS];               // 2*E_row bound
    __shared__ float T_s[ROWS];
    __shared__ unsigned long long best_s[ROWS];
    __shared__ float redf[WAVES];
    __shared__ double l8[WAVES], p8[WAVES];
    __shared__ int okflag, flag_s;

    const int tid = threadIdx.x;
    const int lane = tid & 63;
    const int wv = tid >> 6;
    const int rowbase = blockIdx.x * ROWS;

    if (tid == 0) okflag = 1;
    if (tid < ROWS) best_s[tid] = ~0ull;

    // ---- stage x -> bf16 LDS (coalesced; swizzle as R6) ----
    const float4* xsrc = (const float4*)(x + (size_t)rowbase * D);
#pragma unroll
    for (int i = 0; i < (ROWS * 16) / BLOCK; ++i) {      // 4/thread
        int f = tid + i * BLOCK;
        int r = f >> 4, q = f & 15;
        float4 v = xsrc[f];
        int hb = r * 64 + (((q >> 1) ^ (r & 7)) << 3) + (q & 1) * 4;
        ushort4 h;
        h.x = f2bf(v.x); h.y = f2bf(v.y); h.z = f2bf(v.z); h.w = f2bf(v.w);
        *(ushort4*)&xbf[hb] = h;
    }
    // ---- stage e -> bf16 LDS (coalesced) ----
    const float4* esrc = (const float4*)emb;
#pragma unroll
    for (int i = 0; i < (K * 16) / BLOCK; ++i) {         // 8/thread
        int f = tid + i * BLOCK;
        int c = f >> 4, q = f & 15;
        float4 v = esrc[f];
        int hb = c * 64 + (((q >> 1) ^ (c & 7)) << 3) + (q & 1) * 4;
        ushort4 h;
        h.x = f2bf(v.x); h.y = f2bf(v.y); h.z = f2bf(v.z); h.w = f2bf(v.w);
        *(ushort4*)&ebf[hb] = h;
    }

    // ---- exact numpy sums, 8 lanes per row, coalesced ----
    // lane m owns accumulator r[m] (elements m, m+8, ..., m+56 in order);
    // shfl_xor 1/2/4 tree = ((r0+r1)+(r2+r3))+((r4+r5)+(r6+r7)) exactly.
    {
#pragma clang fp contract(off)
#pragma unroll
        for (int rnd = 0; rnd < (ROWS * 8) / BLOCK; ++rnd) {     // 2 rounds
            int slot = tid + rnd * BLOCK;
            int r = slot >> 3, m = slot & 7;
            const float* xp = x + (size_t)(rowbase + r) * D + m;
            float v = xp[0];
            float rm = v * v, sm = fabsf(v);
#pragma unroll
            for (int t = 1; t < 8; ++t) {
                v = xp[8 * t];
                rm = rm + v * v;
                sm += fabsf(v);
            }
            float o;
            o = __shfl_xor(rm, 1, 64); rm = rm + o;
            o = __shfl_xor(rm, 2, 64); rm = rm + o;
            o = __shfl_xor(rm, 4, 64); rm = rm + o;
            o = __shfl_xor(sm, 1, 64); sm = sm + o;
            o = __shfl_xor(sm, 2, 64); sm = sm + o;
            o = __shfl_xor(sm, 4, 64); sm = sm + o;
            if (m == 0) {
                sx_s[r] = rm;
                // 2*E_row: bf16 RTNE inputs + accum/chain gammas + ulps.
                epre_s[r] = 8.2e-5f * sm + 3.5e-7f * rm + 2e-5f;
            }
        }
#pragma unroll
        for (int rnd = 0; rnd < (K * 8) / BLOCK; ++rnd) {        // 4 rounds
            int slot = tid + rnd * BLOCK;
            int r = slot >> 3, m = slot & 7;
            const float* ep = emb + (size_t)r * D + m;
            float v = ep[0];
            float rm = v * v;
#pragma unroll
            for (int t = 1; t < 8; ++t) {
                v = ep[8 * t];
                rm = rm + v * v;
            }
            float o;
            o = __shfl_xor(rm, 1, 64); rm = rm + o;
            o = __shfl_xor(rm, 2, 64); rm = rm + o;
            o = __shfl_xor(rm, 4, 64); rm = rm + o;
            if (m == 0) se_s[r] = rm;
        }
    }
    __syncthreads();

    // ---- wave-0 self-check of MFMA fragment mapping (asymmetric elem) ----
    if (wv == 0) {
        int r = lane & 15, c = lane & 15, g = lane >> 4;
        bf16x8 a0 = *(const bf16x8*)&xbf[r * 64 + ((g ^ (r & 7)) << 3)];
        bf16x8 a1 = *(const bf16x8*)&xbf[r * 64 + (((4 + g) ^ (r & 7)) << 3)];
        bf16x8 b0 = *(const bf16x8*)&ebf[c * 64 + ((g ^ (c & 7)) << 3)];
        bf16x8 b1 = *(const bf16x8*)&ebf[c * 64 + (((4 + g) ^ (c & 7)) << 3)];
        f32x4 acc = {0.f, 0.f, 0.f, 0.f};
        acc = __builtin_amdgcn_mfma_f32_16x16x32_bf16(a0, b0, acc, 0, 0, 0);
        acc = __builtin_amdgcn_mfma_f32_16x16x32_bf16(a1, b1, acc, 0, 0, 0);
        int myrow = g * 4 + 2, mycode = lane & 15;     // reg 2: asymmetric
        float ref = 0.f;
        for (int dd = 0; dd < 64; ++dd) {
            int s = dd >> 3;
            float xv = bf2f(xbf[myrow * 64 + ((s ^ (myrow & 7)) << 3) + (dd & 7)]);
            float ev = bf2f(ebf[mycode * 64 + ((s ^ (mycode & 7)) << 3) + (dd & 7)]);
            ref = fmaf(xv, ev, ref);
        }
        if (fabsf(acc[2] - ref) > 1e-4f + 1e-2f * fabsf(ref)) okflag = 0;
    }
    __syncthreads();

    if (!okflag) {
        // ---- fallback: exact scalar scan (correct, slow; never expected) ----
        if (tid < ROWS) {
            float xr[D];
            const float4* xp = (const float4*)(x + (size_t)(rowbase + tid) * D);
#pragma unroll
            for (int j = 0; j < 16; ++j) {
                float4 v = xp[j];
                xr[4 * j + 0] = v.x; xr[4 * j + 1] = v.y;
                xr[4 * j + 2] = v.z; xr[4 * j + 3] = v.w;
            }
            const float sxv = sx_s[tid];
            float bdd = INFINITY; int bii = 0;
            for (int k = 0; k < K; ++k) {
                const float4* ep = (const float4*)(emb + (size_t)k * D);
                float a = 0.f;
#pragma unroll
                for (int j = 0; j < 16; ++j) {
                    float4 ev = ep[j];
                    a = fmaf(xr[4 * j + 0], ev.x, a);
                    a = fmaf(xr[4 * j + 1], ev.y, a);
                    a = fmaf(xr[4 * j + 2], ev.z, a);
                    a = fmaf(xr[4 * j + 3], ev.w, a);
                }
                float dc = (sxv + se_s[k]) - 2.0f * a;
                if (dc < bdd) { bdd = dc; bii = k; }
            }
            best_s[tid] = ((unsigned long long)__float_as_uint(bdd) << 32)
                          | (unsigned)bii;
        }
    } else {
        // ---- per-wave fragments: one 16-row tile per wave ----
        const int R = wv * 16;
        const int rr = R + (lane & 15);
        const int sA0 = (lane >> 4), sA1 = 4 + (lane >> 4);
        bf16x8 af0 = *(const bf16x8*)&xbf[rr * 64 + ((sA0 ^ (rr & 7)) << 3)];
        bf16x8 af1 = *(const bf16x8*)&xbf[rr * 64 + ((sA1 ^ (rr & 7)) << 3)];
        float sxr[4], epr[4];
#pragma unroll
        for (int j = 0; j < 4; ++j) {
            int rl = R + (lane >> 4) * 4 + j;
            sxr[j] = sx_s[rl];
            epr[j] = epre_s[rl];
        }

        // ---- sweep 1: per-row min of approx dist over all 512 codes ----
        float minv[4];
#pragma unroll
        for (int j = 0; j < 4; ++j) minv[j] = INFINITY;

#pragma unroll 4
        for (int ct = 0; ct < 32; ++ct) {
            int c = ct * 16 + (lane & 15);
            bf16x8 b0 = *(const bf16x8*)&ebf[c * 64 + ((sA0 ^ (c & 7)) << 3)];
            bf16x8 b1 = *(const bf16x8*)&ebf[c * 64 + ((sA1 ^ (c & 7)) << 3)];
            float sev = se_s[c];
            f32x4 acc = {0.f, 0.f, 0.f, 0.f};
            acc = __builtin_amdgcn_mfma_f32_16x16x32_bf16(af0, b0, acc, 0, 0, 0);
            acc = __builtin_amdgcn_mfma_f32_16x16x32_bf16(af1, b1, acc, 0, 0, 0);
#pragma unroll
            for (int j = 0; j < 4; ++j) {
                float dd = (sxr[j] + sev) - 2.0f * acc[j];
                minv[j] = fminf(minv[j], dd);
            }
        }
        // col-reduce across the 16 lanes sharing each row quartet
#pragma unroll
        for (int off = 1; off < 16; off <<= 1)
#pragma unroll
            for (int j = 0; j < 4; ++j)
                minv[j] = fminf(minv[j], __shfl_xor(minv[j], off, 64));
        if ((lane & 15) == 0) {
#pragma unroll
            for (int j = 0; j < 4; ++j) {
                int rl = R + (lane >> 4) * 4 + j;
                T_s[rl] = minv[j] + epr[j];
            }
        }
        __syncthreads();

        // ---- sweep 2: recompute; pairs with d<=T -> exact recheck ----
        float Tr[4];
#pragma unroll
        for (int j = 0; j < 4; ++j)
            Tr[j] = T_s[R + (lane >> 4) * 4 + j];

#pragma unroll 4
        for (int ct = 0; ct < 32; ++ct) {
            int c = ct * 16 + (lane & 15);
            bf16x8 b0 = *(const bf16x8*)&ebf[c * 64 + ((sA0 ^ (c & 7)) << 3)];
            bf16x8 b1 = *(const bf16x8*)&ebf[c * 64 + ((sA1 ^ (c & 7)) << 3)];
            float sev = se_s[c];
            f32x4 acc = {0.f, 0.f, 0.f, 0.f};
            acc = __builtin_amdgcn_mfma_f32_16x16x32_bf16(af0, b0, acc, 0, 0, 0);
            acc = __builtin_amdgcn_mfma_f32_16x16x32_bf16(af1, b1, acc, 0, 0, 0);
#pragma unroll
            for (int j = 0; j < 4; ++j) {
                float dd = (sxr[j] + sev) - 2.0f * acc[j];
                if (dd <= Tr[j]) {
                    int rl = R + (lane >> 4) * 4 + j;
                    exact_merge(x, emb, rowbase + rl, c,
                                sxr[j], sev, &best_s[rl]);
                }
            }
        }
    }
    __syncthreads();        // best_s final; bf16 tiles dead from here

    // ---- epilogue phase 1: coalesced gather + q write + dx -> LDS ----
    {
        const int row = tid >> 2, ch = tid & 3;
        const int bi = (int)(best_s[row] & 0xFFFFFFFFull);
        const int rowg = rowbase + row;
        const float4* xp = (const float4*)(x + (size_t)rowg * D) + ch * 4;
        const float4* ep = (const float4*)(emb + (size_t)bi * D) + ch * 4;
        float4* qp = (float4*)(q_out + (size_t)rowg * D) + ch * 4;
        float* dxrow = dxs + row * 68 + ch * 16;
#pragma unroll
        for (int jj = 0; jj < 4; ++jj) {
            float4 xv = xp[jj];
            float4 e  = ep[jj];
            float4 dx;
            dx.x = e.x - xv.x; dx.y = e.y - xv.y;
            dx.z = e.z - xv.z; dx.w = e.w - xv.w;
            float4 qs;  // straight-through: x + (q - x), ref rounding
            qs.x = xv.x + dx.x; qs.y = xv.y + dx.y;
            qs.z = xv.z + dx.z; qs.w = xv.w + dx.w;
            qp[jj] = qs;
            *(float4*)(dxrow + jj * 4) = dx;
        }
    }
    __syncthreads();

    // ---- epilogue phase 2: per-row exact loss chain (order as R0-R6) ----
    float s_loss = 0.f;
    if (tid < ROWS) {
        const int bi = (int)(best_s[tid] & 0xFFFFFFFFull);
        atomicAdd(&part_hist[(blockIdx.x & (NPART - 1)) * K + bi], 1);
        const float4* dx4 = (const float4*)(dxs + tid * 68);
#pragma unroll
        for (int jc = 0; jc < 16; ++jc) {
            float4 d4 = dx4[jc];
            s_loss = fmaf(d4.x, d4.x, s_loss);
            s_loss = fmaf(d4.y, d4.y, s_loss);
            s_loss = fmaf(d4.z, d4.z, s_loss);
            s_loss = fmaf(d4.w, d4.w, s_loss);
        }
        idx_out[rowbase + tid] = (float)bi;
    }

    for (int off = 32; off; off >>= 1) s_loss += __shfl_down(s_loss, off, 64);
    if (lane == 0) redf[wv] = s_loss;
    __syncthreads();
    if (tid == 0) {
        float tsum = 0.f;
#pragma unroll
        for (int w = 0; w < WAVES; ++w) tsum += redf[w];
        block_sums[blockIdx.x] = tsum;
    }

    // ---- completion ticket; last block finalizes (R4-R6 validated) ----
    __threadfence();
    __syncthreads();
    if (tid == 0) flag_s = atomicAdd(done_ctr, 1);
    __syncthreads();
    if (flag_s != (int)gridDim.x - 1) return;

    __threadfence();
    const int nblocks = (int)gridDim.x;
    double ls = 0.0;
    for (int i = tid; i < nblocks; i += BLOCK)
        ls += (double)__hip_atomic_load(&block_sums[i], __ATOMIC_RELAXED,
                                        __HIP_MEMORY_SCOPE_AGENT);
    double ps = 0.0;
    for (int k2 = tid; k2 < K; k2 += BLOCK) {
        int c = 0;
#pragma unroll
        for (int p = 0; p < NPART; ++p)
            c += __hip_atomic_load(&part_hist[p * K + k2], __ATOMIC_RELAXED,
                                   __HIP_MEMORY_SCOPE_AGENT);
        float pv = (float)c * inv_rows;
        ps += (double)(pv * logf(pv + 1e-10f));
    }
    for (int off = 32; off; off >>= 1) {
        ls += __shfl_down(ls, off, 64);
        ps += __shfl_down(ps, off, 64);
    }
    if (lane == 0) { l8[wv] = ls; p8[wv] = ps; }
    __syncthreads();
    if (tid == 0) {
        double L = 0.0, P = 0.0;
#pragma unroll
        for (int w = 0; w < WAVES; ++w) { L += l8[w]; P += p8[w]; }
        // loss = q_latent + 0.25*e_latent; forward values identical
        *out_loss = 1.25f * (float)(L * (double)inv_nelem);
        *out_perp = expf((float)(-P));
    }
}

extern "C" void kernel_launch(void* const* d_in, const int* in_sizes, int n_in,
                              void* d_out, int out_size, void* d_ws, size_t ws_size,
                              hipStream_t stream) {
    const float* x   = (const float*)d_in[0];
    const float* emb = (const float*)d_in[1];
    const int N = in_sizes[0] / D;          // 65536 rows
    const int nblocks = N / ROWS;           // 256

    float* out      = (float*)d_out;
    float* loss_out = out;                  // [0]
    float* q_out    = out + 1;              // [1 .. N*D]
    float* perp_out = out + 1 + (size_t)N * D;
    float* idx_out  = perp_out + 1;         // [.. + N]

    // ws: [block_sums: nblocks f32 | pad 256B][part_hist: 32*512 i32][ctr]
    float* block_sums = (float*)d_ws;
    int*   part_hist  = (int*)((char*)d_ws +
                               (((size_t)nblocks * 4 + 255) & ~(size_t)255));
    int*   done_ctr   = part_hist + (size_t)NPART * K;

    hipMemsetAsync(part_hist, 0, (size_t)NPART * K * sizeof(int) + sizeof(int),
                   stream);
    vq_fused<<<nblocks, BLOCK, 0, stream>>>(x, emb, q_out, idx_out,
                                            block_sums, part_hist, done_ctr,
                                            loss_out, perp_out,
                                            1.0f / (float)((size_t)N * D),
                                            1.0f / (float)N);
}

// Round 9
// 201.407 us; speedup vs baseline: 1.6381x; 1.6381x over previous
//
#include <hip/hip_runtime.h>
#include <math.h>

#define D 64
#define K 512
#define BLOCK 256
#define ROWS 128            // rows per block
#define KT 128              // codes per staged e-tile
#define NKT (K / KT)        // 4
#define NPART 32

// Bit-level emulation of the harness's numpy fp32 reference (validated at
// absmax 0.0 across R0-R8):
//   dist[i,k] = fp32( fp32(sx[i] + se[k]) - 2*dot[i,k] )
// sx/se = numpy pairwise sums (8-accumulator kernel, contraction OFF),
// dot = sequential single-accumulator fmaf chain over j=0..63 (ascending).
// argmin strict-<, first occurrence (all merges lexicographic on (d,k)).
//
// Round-9: the MFMA-screen line (R6-R8) is abandoned — latency-crippled at
// 235-295us with all pipes <11% despite a correct algorithm. This kernel is
// the measured champion (R2: 81.5us scan, 104 VGPR, no spill) with only
// hardware-validated deltas:
//  - sx/se via 8-lanes-per-row coalesced global loads + shfl_xor 1/2/4 tree
//    (exactly reproduces np's 8-acc pairwise bracketing; absmax-0.0-validated
//    in R8). Removes R2's 6.66M LDS conflict cycles and the in-loop se pass.
//  - per-row direct atomics into 32 partial histograms (validated R4+).
//  - finalize fused into last-arriving block via ticket (validated R4+).
// Inner loop, swizzles, barriers, epilogue: R2 verbatim.

__global__ __launch_bounds__(BLOCK, 2) void vq_fused(
    const float* __restrict__ x, const float* __restrict__ emb,
    float* __restrict__ q_out, float* __restrict__ idx_out,
    float* __restrict__ block_sums, int* __restrict__ part_hist,
    int* __restrict__ done_ctr,
    float* __restrict__ out_loss, float* __restrict__ out_perp,
    float inv_nelem, float inv_rows)
{
    // swizzled tiles: float4 index = row*16 + (jc ^ ((row>>3)&7))
    __shared__ float4 xs4[ROWS * 16];   // 32 KB
    __shared__ float4 es4[KT * 16];     // 32 KB (aliased as bests[] later)
    __shared__ float sx_s[ROWS];        // exact numpy ||x||^2
    __shared__ float se_s[K];           // exact numpy ||e||^2, all codes
    __shared__ float redf[BLOCK / 64];
    __shared__ double l8[BLOCK / 64], p8[BLOCK / 64];
    __shared__ int flag_s;

    const int tid = threadIdx.x;
    const int lane = tid & 63;
    const int wv = tid >> 6;
    const int rg = tid & 15;            // row-group: rows rg*8..rg*8+7
    const int cg = tid >> 4;            // code-group 0..15
    const int rowbase = blockIdx.x * ROWS;

    // ---- stage x tile (coalesced global -> swizzled LDS), R2 verbatim ----
    const float4* xsrc = (const float4*)(x + (size_t)rowbase * D);
#pragma unroll
    for (int i = 0; i < (ROWS * 16) / BLOCK; ++i) {      // 8 float4/thread
        int f = tid + i * BLOCK;
        int row = f >> 4, jc = f & 15;
        xs4[row * 16 + (jc ^ ((row >> 3) & 7))] = xsrc[f];
    }

    // ---- exact numpy sums, 8 lanes per row, coalesced global loads ----
    // lane m owns accumulator r[m] (elements m, m+8, ..., m+56, in order);
    // shfl_xor 1/2/4 tree = ((r0+r1)+(r2+r3))+((r4+r5)+(r6+r7)) exactly.
    {
#pragma clang fp contract(off)
#pragma unroll
        for (int rnd = 0; rnd < (ROWS * 8) / BLOCK; ++rnd) {     // 4 rounds
            int slot = tid + rnd * BLOCK;
            int r = slot >> 3, m = slot & 7;
            const float* xp = x + (size_t)(rowbase + r) * D + m;
            float v = xp[0];
            float rm = v * v;
#pragma unroll
            for (int t = 1; t < 8; ++t) {
                v = xp[8 * t];
                rm = rm + v * v;
            }
            float o;
            o = __shfl_xor(rm, 1, 64); rm = rm + o;
            o = __shfl_xor(rm, 2, 64); rm = rm + o;
            o = __shfl_xor(rm, 4, 64); rm = rm + o;
            if (m == 0) sx_s[r] = rm;
        }
#pragma unroll
        for (int rnd = 0; rnd < (K * 8) / BLOCK; ++rnd) {        // 16 rounds
            int slot = tid + rnd * BLOCK;
            int r = slot >> 3, m = slot & 7;
            const float* ep = emb + (size_t)r * D + m;
            float v = ep[0];
            float rm = v * v;
#pragma unroll
            for (int t = 1; t < 8; ++t) {
                v = ep[8 * t];
                rm = rm + v * v;
            }
            float o;
            o = __shfl_xor(rm, 1, 64); rm = rm + o;
            o = __shfl_xor(rm, 2, 64); rm = rm + o;
            o = __shfl_xor(rm, 4, 64); rm = rm + o;
            if (m == 0) se_s[r] = rm;
        }
    }
    __syncthreads();

    float bd[8], bkf[8];
#pragma unroll
    for (int r = 0; r < 8; ++r) { bd[r] = INFINITY; bkf[r] = 0.f; }

    const int xbase = rg * 8, ebase = cg * 8;
    const int swx0 = rg & 7, swe0 = cg & 7;

#pragma unroll 1
    for (int kt = 0; kt < NKT; ++kt) {
        // ---- stage e tile (prev reads done: post-inner barrier) ----
        const float4* esrc = (const float4*)(emb + (size_t)kt * KT * D);
#pragma unroll
        for (int i = 0; i < (KT * 16) / BLOCK; ++i) {
            int f = tid + i * BLOCK;
            int row = f >> 4, jc = f & 15;
            es4[row * 16 + (jc ^ ((row >> 3) & 7))] = esrc[f];
        }
        __syncthreads();

        float acc[8][8];
#pragma unroll
        for (int r = 0; r < 8; ++r)
#pragma unroll
            for (int c = 0; c < 8; ++c) acc[r][c] = 0.f;

        // 16:1 FMA:DS inner loop; each acc is a sequential ascending-j chain
#pragma unroll 2
        for (int jc = 0; jc < 16; ++jc) {
            float4 xa[8], eb[8];
#pragma unroll
            for (int r = 0; r < 8; ++r)
                xa[r] = xs4[(xbase + r) * 16 + (jc ^ swx0)];
#pragma unroll
            for (int c = 0; c < 8; ++c)
                eb[c] = es4[(ebase + c) * 16 + (jc ^ swe0)];
#pragma unroll
            for (int r = 0; r < 8; ++r)
#pragma unroll
                for (int c = 0; c < 8; ++c) {
                    acc[r][c] = fmaf(xa[r].x, eb[c].x, acc[r][c]);
                    acc[r][c] = fmaf(xa[r].y, eb[c].y, acc[r][c]);
                    acc[r][c] = fmaf(xa[r].z, eb[c].z, acc[r][c]);
                    acc[r][c] = fmaf(xa[r].w, eb[c].w, acc[r][c]);
                }
        }
        __syncthreads();    // all es4 reads done

        // dist + running first-min (kt ascending, c ascending, strict <)
        const int kglob = kt * KT + ebase;
        float sev[8];
#pragma unroll
        for (int c = 0; c < 8; ++c) sev[c] = se_s[kglob + c];
#pragma unroll
        for (int r = 0; r < 8; ++r) {
            float sxv = sx_s[xbase + r];
#pragma unroll
            for (int c = 0; c < 8; ++c) {
                float dcur = (sxv + sev[c]) - 2.0f * acc[r][c];  // ref rounding
                if (dcur < bd[r]) { bd[r] = dcur; bkf[r] = (float)(kglob + c); }
            }
        }
    }

    // ---- cross-thread argmin: lexicographic (d, k) over 16 code-groups ----
    float2* bests = (float2*)es4;       // 16 KB alias, e-tiles dead now
#pragma unroll
    for (int r = 0; r < 8; ++r)
        bests[(xbase + r) * 16 + cg] = make_float2(bd[r], bkf[r]);
    __syncthreads();

    float s = 0.f;
    if (tid < ROWS) {
        float bdd = INFINITY, bjf = 1e30f;
#pragma unroll
        for (int g = 0; g < 16; ++g) {
            float2 p = bests[tid * 16 + g];
            if (p.x < bdd || (p.x == bdd && p.y < bjf)) { bdd = p.x; bjf = p.y; }
        }
        const int bi = (int)bjf;
        atomicAdd(&part_hist[(blockIdx.x & (NPART - 1)) * K + bi], 1);

        const int rowg = rowbase + tid;
        const float4* ep = (const float4*)(emb + (size_t)bi * D);
        float4* qp = (float4*)(q_out + (size_t)rowg * D);
        const int sw = (tid >> 3) & 7;
#pragma unroll
        for (int jc = 0; jc < 16; ++jc) {
            float4 xv = xs4[tid * 16 + (jc ^ sw)];   // bit-identical x copy
            float4 e  = ep[jc];
            float dx0 = e.x - xv.x, dx1 = e.y - xv.y;
            float dx2 = e.z - xv.z, dx3 = e.w - xv.w;
            s = fmaf(dx0, dx0, s);
            s = fmaf(dx1, dx1, s);
            s = fmaf(dx2, dx2, s);
            s = fmaf(dx3, dx3, s);
            float4 qs;  // straight-through: x + (q - x)
            qs.x = xv.x + dx0; qs.y = xv.y + dx1;
            qs.z = xv.z + dx2; qs.w = xv.w + dx3;
            qp[jc] = qs;
        }
        idx_out[rowg] = (float)bi;
    }

    // ---- loss partial (inactive waves contribute 0) ----
    for (int off = 32; off; off >>= 1) s += __shfl_down(s, off, 64);
    if (lane == 0) redf[wv] = s;
    __syncthreads();
    if (tid == 0) {
        float t = 0.f;
#pragma unroll
        for (int w = 0; w < BLOCK / 64; ++w) t += redf[w];
        block_sums[blockIdx.x] = t;
    }

    // ---- completion ticket; last-arriving block finalizes (R4+ valid) ----
    __threadfence();
    __syncthreads();
    if (tid == 0) flag_s = atomicAdd(done_ctr, 1);
    __syncthreads();
    if (flag_s != (int)gridDim.x - 1) return;

    __threadfence();        // acquire side
    const int nblocks = (int)gridDim.x;
    double ls = 0.0;
    for (int i = tid; i < nblocks; i += BLOCK)
        ls += (double)__hip_atomic_load(&block_sums[i], __ATOMIC_RELAXED,
                                        __HIP_MEMORY_SCOPE_AGENT);
    double ps = 0.0;
    for (int k2 = tid; k2 < K; k2 += BLOCK) {
        int c = 0;
#pragma unroll
        for (int p = 0; p < NPART; ++p)
            c += __hip_atomic_load(&part_hist[p * K + k2], __ATOMIC_RELAXED,
                                   __HIP_MEMORY_SCOPE_AGENT);
        float pv = (float)c * inv_rows;
        ps += (double)(pv * logf(pv + 1e-10f));
    }
    for (int off = 32; off; off >>= 1) {
        ls += __shfl_down(ls, off, 64);
        ps += __shfl_down(ps, off, 64);
    }
    if (lane == 0) { l8[wv] = ls; p8[wv] = ps; }
    __syncthreads();
    if (tid == 0) {
        double L = 0.0, P = 0.0;
#pragma unroll
        for (int w = 0; w < BLOCK / 64; ++w) { L += l8[w]; P += p8[w]; }
        // loss = q_latent + 0.25*e_latent; forward values identical
        *out_loss = 1.25f * (float)(L * (double)inv_nelem);
        *out_perp = expf((float)(-P));
    }
}

extern "C" void kernel_launch(void* const* d_in, const int* in_sizes, int n_in,
                              void* d_out, int out_size, void* d_ws, size_t ws_size,
                              hipStream_t stream) {
    const float* x   = (const float*)d_in[0];
    const float* emb = (const float*)d_in[1];
    const int N = in_sizes[0] / D;          // 65536 rows
    const int nblocks = N / ROWS;           // 512

    float* out      = (float*)d_out;
    float* loss_out = out;                  // [0]
    float* q_out    = out + 1;              // [1 .. N*D]
    float* perp_out = out + 1 + (size_t)N * D;
    float* idx_out  = perp_out + 1;         // [.. + N]

    // ws: [block_sums: nblocks f32 | pad 256B][part_hist: 32*512 i32][ctr]
    float* block_sums = (float*)d_ws;
    int*   part_hist  = (int*)((char*)d_ws +
                               (((size_t)nblocks * 4 + 255) & ~(size_t)255));
    int*   done_ctr   = part_hist + (size_t)NPART * K;

    // one memset zeroes part_hist AND the ticket counter (contiguous)
    hipMemsetAsync(part_hist, 0, (size_t)NPART * K * sizeof(int) + sizeof(int),
                   stream);
    vq_fused<<<nblocks, BLOCK, 0, stream>>>(x, emb, q_out, idx_out,
                                            block_sums, part_hist, done_ctr,
                                            loss_out, perp_out,
                                            1.0f / (float)((size_t)N * D),
                                            1.0f / (float)N);
}

// Round 10
// 199.072 us; speedup vs baseline: 1.6573x; 1.0117x over previous
//
#include <hip/hip_runtime.h>
#include <math.h>

#define D 64
#define K 512
#define BLOCK 256
#define ROWS 128            // rows per block
#define KT 128              // codes per staged e-tile
#define NKT (K / KT)        // 4
#define NPART 32
#define BSTRIDE 17          // bests[] float2 stride (16 -> 17 kills 16/64-way)

// Bit-level emulation of the harness's numpy fp32 reference (validated at
// absmax 0.0 across R0-R9):
//   dist[i,k] = fp32( fp32(sx[i] + se[k]) - 2*dot[i,k] )
// sx/se = numpy pairwise sums (8-accumulator kernel, contraction OFF),
// dot = sequential single-accumulator fmaf chain over j=0..63 (ascending).
// argmin strict-<, first occurrence (all merges lexicographic on (d,k)).
//
// Round-10: R9 = R2-structure + fused finalize + shfl prologue, but the
// fully-unrolled prologue spilled (VGPR 104->128, +16MB scratch writeback,
// VALU-issue unchanged at ~45us while wall doubled). Fixes, everything else
// R9/R2 verbatim:
//  - #pragma unroll 1 on prologue round-loops (kills the spill);
//  - bests[] stride 17 (old stride-16 float2 layout was a 16-way write /
//    64-way read bank conflict -- the real source of the ~5.7M conflicts);
//  - staging reads pre-swizzled at the GLOBAL address (XOR involution;
//    LDS content bit-identical), LDS stores linear.

__global__ __launch_bounds__(BLOCK, 2) void vq_fused(
    const float* __restrict__ x, const float* __restrict__ emb,
    float* __restrict__ q_out, float* __restrict__ idx_out,
    float* __restrict__ block_sums, int* __restrict__ part_hist,
    int* __restrict__ done_ctr,
    float* __restrict__ out_loss, float* __restrict__ out_perp,
    float inv_nelem, float inv_rows)
{
    // swizzled tiles: float4 index = row*16 + (jc ^ ((row>>3)&7))
    __shared__ float4 xs4[ROWS * 16];   // 32 KB
    __shared__ float4 es4[KT * 16];     // 32 KB (aliased as bests[] later)
    __shared__ float sx_s[ROWS];        // exact numpy ||x||^2
    __shared__ float se_s[K];           // exact numpy ||e||^2, all codes
    __shared__ float redf[BLOCK / 64];
    __shared__ double l8[BLOCK / 64], p8[BLOCK / 64];
    __shared__ int flag_s;

    const int tid = threadIdx.x;
    const int lane = tid & 63;
    const int wv = tid >> 6;
    const int rg = tid & 15;            // row-group: rows rg*8..rg*8+7
    const int cg = tid >> 4;            // code-group 0..15
    const int rowbase = blockIdx.x * ROWS;

    // ---- stage x tile: pre-swizzled global read, LINEAR LDS store ----
    // LDS[row*16+s] = G[row*16 + (s^sw)]  <=>  LDS[row*16+(jc^sw)] = G[row,jc]
    const float4* xsrc = (const float4*)(x + (size_t)rowbase * D);
#pragma unroll
    for (int i = 0; i < (ROWS * 16) / BLOCK; ++i) {      // 8 float4/thread
        int f = tid + i * BLOCK;
        int row = f >> 4, s = f & 15;
        xs4[f] = xsrc[row * 16 + (s ^ ((row >> 3) & 7))];
    }

    // ---- exact numpy sums, 8 lanes per row, coalesced global loads ----
    // lane m owns accumulator r[m] (elements m, m+8, ..., m+56, in order);
    // shfl_xor 1/2/4 tree = ((r0+r1)+(r2+r3))+((r4+r5)+(r6+r7)) exactly.
    // unroll 1: keep loads of different rounds out of flight (R9 spilled).
    {
#pragma clang fp contract(off)
#pragma unroll 1
        for (int rnd = 0; rnd < (ROWS * 8) / BLOCK; ++rnd) {     // 4 rounds
            int slot = tid + rnd * BLOCK;
            int r = slot >> 3, m = slot & 7;
            const float* xp = x + (size_t)(rowbase + r) * D + m;
            float v = xp[0];
            float rm = v * v;
#pragma unroll
            for (int t = 1; t < 8; ++t) {
                v = xp[8 * t];
                rm = rm + v * v;
            }
            float o;
            o = __shfl_xor(rm, 1, 64); rm = rm + o;
            o = __shfl_xor(rm, 2, 64); rm = rm + o;
            o = __shfl_xor(rm, 4, 64); rm = rm + o;
            if (m == 0) sx_s[r] = rm;
        }
#pragma unroll 1
        for (int rnd = 0; rnd < (K * 8) / BLOCK; ++rnd) {        // 16 rounds
            int slot = tid + rnd * BLOCK;
            int r = slot >> 3, m = slot & 7;
            const float* ep = emb + (size_t)r * D + m;
            float v = ep[0];
            float rm = v * v;
#pragma unroll
            for (int t = 1; t < 8; ++t) {
                v = ep[8 * t];
                rm = rm + v * v;
            }
            float o;
            o = __shfl_xor(rm, 1, 64); rm = rm + o;
            o = __shfl_xor(rm, 2, 64); rm = rm + o;
            o = __shfl_xor(rm, 4, 64); rm = rm + o;
            if (m == 0) se_s[r] = rm;
        }
    }
    __syncthreads();

    float bd[8], bkf[8];
#pragma unroll
    for (int r = 0; r < 8; ++r) { bd[r] = INFINITY; bkf[r] = 0.f; }

    const int xbase = rg * 8, ebase = cg * 8;
    const int swx0 = rg & 7, swe0 = cg & 7;

#pragma unroll 1
    for (int kt = 0; kt < NKT; ++kt) {
        // ---- stage e tile: pre-swizzled global read, linear LDS store ----
        const float4* esrc = (const float4*)(emb + (size_t)kt * KT * D);
#pragma unroll
        for (int i = 0; i < (KT * 16) / BLOCK; ++i) {
            int f = tid + i * BLOCK;
            int row = f >> 4, s = f & 15;
            es4[f] = esrc[row * 16 + (s ^ ((row >> 3) & 7))];
        }
        __syncthreads();

        float acc[8][8];
#pragma unroll
        for (int r = 0; r < 8; ++r)
#pragma unroll
            for (int c = 0; c < 8; ++c) acc[r][c] = 0.f;

        // 16:1 FMA:DS inner loop; each acc is a sequential ascending-j chain
#pragma unroll 2
        for (int jc = 0; jc < 16; ++jc) {
            float4 xa[8], eb[8];
#pragma unroll
            for (int r = 0; r < 8; ++r)
                xa[r] = xs4[(xbase + r) * 16 + (jc ^ swx0)];
#pragma unroll
            for (int c = 0; c < 8; ++c)
                eb[c] = es4[(ebase + c) * 16 + (jc ^ swe0)];
#pragma unroll
            for (int r = 0; r < 8; ++r)
#pragma unroll
                for (int c = 0; c < 8; ++c) {
                    acc[r][c] = fmaf(xa[r].x, eb[c].x, acc[r][c]);
                    acc[r][c] = fmaf(xa[r].y, eb[c].y, acc[r][c]);
                    acc[r][c] = fmaf(xa[r].z, eb[c].z, acc[r][c]);
                    acc[r][c] = fmaf(xa[r].w, eb[c].w, acc[r][c]);
                }
        }
        __syncthreads();    // all es4 reads done

        // dist + running first-min (kt ascending, c ascending, strict <)
        const int kglob = kt * KT + ebase;
        float sev[8];
#pragma unroll
        for (int c = 0; c < 8; ++c) sev[c] = se_s[kglob + c];
#pragma unroll
        for (int r = 0; r < 8; ++r) {
            float sxv = sx_s[xbase + r];
#pragma unroll
            for (int c = 0; c < 8; ++c) {
                float dcur = (sxv + sev[c]) - 2.0f * acc[r][c];  // ref rounding
                if (dcur < bd[r]) { bd[r] = dcur; bkf[r] = (float)(kglob + c); }
            }
        }
    }

    // ---- cross-thread argmin: lexicographic (d, k) over 16 code-groups ----
    float2* bests = (float2*)es4;   // alias; 128*17*8B = 17.4 KB < 32 KB
#pragma unroll
    for (int r = 0; r < 8; ++r)
        bests[(xbase + r) * BSTRIDE + cg] = make_float2(bd[r], bkf[r]);
    __syncthreads();

    float s = 0.f;
    if (tid < ROWS) {
        float bdd = INFINITY, bjf = 1e30f;
#pragma unroll
        for (int g = 0; g < 16; ++g) {
            float2 p = bests[tid * BSTRIDE + g];
            if (p.x < bdd || (p.x == bdd && p.y < bjf)) { bdd = p.x; bjf = p.y; }
        }
        const int bi = (int)bjf;
        atomicAdd(&part_hist[(blockIdx.x & (NPART - 1)) * K + bi], 1);

        const int rowg = rowbase + tid;
        const float4* ep = (const float4*)(emb + (size_t)bi * D);
        float4* qp = (float4*)(q_out + (size_t)rowg * D);
        const int sw = (tid >> 3) & 7;
#pragma unroll
        for (int jc = 0; jc < 16; ++jc) {
            float4 xv = xs4[tid * 16 + (jc ^ sw)];   // bit-identical x copy
            float4 e  = ep[jc];
            float dx0 = e.x - xv.x, dx1 = e.y - xv.y;
            float dx2 = e.z - xv.z, dx3 = e.w - xv.w;
            s = fmaf(dx0, dx0, s);
            s = fmaf(dx1, dx1, s);
            s = fmaf(dx2, dx2, s);
            s = fmaf(dx3, dx3, s);
            float4 qs;  // straight-through: x + (q - x)
            qs.x = xv.x + dx0; qs.y = xv.y + dx1;
            qs.z = xv.z + dx2; qs.w = xv.w + dx3;
            qp[jc] = qs;
        }
        idx_out[rowg] = (float)bi;
    }

    // ---- loss partial (inactive waves contribute 0) ----
    for (int off = 32; off; off >>= 1) s += __shfl_down(s, off, 64);
    if (lane == 0) redf[wv] = s;
    __syncthreads();
    if (tid == 0) {
        float t = 0.f;
#pragma unroll
        for (int w = 0; w < BLOCK / 64; ++w) t += redf[w];
        block_sums[blockIdx.x] = t;
    }

    // ---- completion ticket; last-arriving block finalizes (R4+ valid) ----
    __threadfence();
    __syncthreads();
    if (tid == 0) flag_s = atomicAdd(done_ctr, 1);
    __syncthreads();
    if (flag_s != (int)gridDim.x - 1) return;

    __threadfence();        // acquire side
    const int nblocks = (int)gridDim.x;
    double ls = 0.0;
    for (int i = tid; i < nblocks; i += BLOCK)
        ls += (double)__hip_atomic_load(&block_sums[i], __ATOMIC_RELAXED,
                                        __HIP_MEMORY_SCOPE_AGENT);
    double ps = 0.0;
    for (int k2 = tid; k2 < K; k2 += BLOCK) {
        int c = 0;
#pragma unroll
        for (int p = 0; p < NPART; ++p)
            c += __hip_atomic_load(&part_hist[p * K + k2], __ATOMIC_RELAXED,
                                   __HIP_MEMORY_SCOPE_AGENT);
        float pv = (float)c * inv_rows;
        ps += (double)(pv * logf(pv + 1e-10f));
    }
    for (int off = 32; off; off >>= 1) {
        ls += __shfl_down(ls, off, 64);
        ps += __shfl_down(ps, off, 64);
    }
    if (lane == 0) { l8[wv] = ls; p8[wv] = ps; }
    __syncthreads();
    if (tid == 0) {
        double L = 0.0, P = 0.0;
#pragma unroll
        for (int w = 0; w < BLOCK / 64; ++w) { L += l8[w]; P += p8[w]; }
        // loss = q_latent + 0.25*e_latent; forward values identical
        *out_loss = 1.25f * (float)(L * (double)inv_nelem);
        *out_perp = expf((float)(-P));
    }
}

extern "C" void kernel_launch(void* const* d_in, const int* in_sizes, int n_in,
                              void* d_out, int out_size, void* d_ws, size_t ws_size,
                              hipStream_t stream) {
    const float* x   = (const float*)d_in[0];
    const float* emb = (const float*)d_in[1];
    const int N = in_sizes[0] / D;          // 65536 rows
    const int nblocks = N / ROWS;           // 512

    float* out      = (float*)d_out;
    float* loss_out = out;                  // [0]
    float* q_out    = out + 1;              // [1 .. N*D]
    float* perp_out = out + 1 + (size_t)N * D;
    float* idx_out  = perp_out + 1;         // [.. + N]

    // ws: [block_sums: nblocks f32 | pad 256B][part_hist: 32*512 i32][ctr]
    float* block_sums = (float*)d_ws;
    int*   part_hist  = (int*)((char*)d_ws +
                               (((size_t)nblocks * 4 + 255) & ~(size_t)255));
    int*   done_ctr   = part_hist + (size_t)NPART * K;

    // one memset zeroes part_hist AND the ticket counter (contiguous)
    hipMemsetAsync(part_hist, 0, (size_t)NPART * K * sizeof(int) + sizeof(int),
                   stream);
    vq_fused<<<nblocks, BLOCK, 0, stream>>>(x, emb, q_out, idx_out,
                                            block_sums, part_hist, done_ctr,
                                            loss_out, perp_out,
                                            1.0f / (float)((size_t)N * D),
                                            1.0f / (float)N);
}

// Round 11
// 140.431 us; speedup vs baseline: 2.3493x; 1.4176x over previous
//
#include <hip/hip_runtime.h>
#include <math.h>

#define D 64
#define K 512
#define BLOCK 256
#define ROWS 128            // rows per block
#define KT 128              // codes per staged e-tile
#define NKT (K / KT)        // 4
#define NPART 32
#define BSTRIDE 17          // bests[] float2 stride: read bank-pair = 2*tid%32

// Bit-level emulation of the harness's numpy fp32 reference (validated at
// absmax 0.0 across R0-R10):
//   dist[i,k] = fp32( fp32(sx[i] + se[k]) - 2*dot[i,k] )
// sx/se = numpy pairwise sums (8-accumulator kernel, contraction OFF),
// dot = sequential single-accumulator fmaf chain over j=0..63 (ascending).
// argmin strict-<, first occurrence (all merges lexicographic on (d,k)).
//
// Round-11: R4/R9/R10 all landed at ~150us with DIFFERENT inner loops but
// the SAME fused tail (__threadfence + ticket). threadfence at agent scope
// emits buffer_wbl2 = full per-XCD L2 writeback; 64 blocks/XCD flushing L2
// in their critical path explains both the +16MB write traffic (q lines
// flushed, re-dirtied, re-flushed) and the ~70us stall at unchanged VALU
// busy. This round reverts to the MEASURED-fast split graph (R2: scan 81.5us
// + tiny finalize, no fence) keeping only validated in-kernel deltas:
//  - shfl-tree sx/se prologue from coalesced global (bit-exact, R8-R10);
//  - pre-swizzled global staging reads, linear LDS stores (content identical);
//  - bests[] stride 17 (old stride 16: 64-way read conflict).

__global__ __launch_bounds__(BLOCK, 2) void vq_fused(
    const float* __restrict__ x, const float* __restrict__ emb,
    float* __restrict__ q_out, float* __restrict__ idx_out,
    float* __restrict__ block_sums, int* __restrict__ part_hist, int N)
{
    // swizzled tiles: logical float4 index = row*16 + (jc ^ ((row>>3)&7))
    __shared__ float4 xs4[ROWS * 16];   // 32 KB
    __shared__ float4 es4[KT * 16];     // 32 KB (aliased as bests[] later)
    __shared__ float sx_s[ROWS];        // exact numpy ||x||^2
    __shared__ float se_s[K];           // exact numpy ||e||^2, all codes
    __shared__ int hist[K];
    __shared__ float redf[BLOCK / 64];

    const int tid = threadIdx.x;
    const int lane = tid & 63;
    const int wv = tid >> 6;
    const int rg = tid & 15;            // row-group: rows rg*8..rg*8+7
    const int cg = tid >> 4;            // code-group 0..15
    const int rowbase = blockIdx.x * ROWS;

    for (int k2 = tid; k2 < K; k2 += BLOCK) hist[k2] = 0;

    // ---- stage x tile: pre-swizzled global read, LINEAR LDS store ----
    // LDS[row*16+s] = G[row*16+(s^sw)]  <=>  LDS[row*16+(jc^sw)] = G[row,jc]
    const float4* xsrc = (const float4*)(x + (size_t)rowbase * D);
#pragma unroll
    for (int i = 0; i < (ROWS * 16) / BLOCK; ++i) {      // 8 float4/thread
        int f = tid + i * BLOCK;
        int row = f >> 4, s = f & 15;
        xs4[f] = xsrc[row * 16 + (s ^ ((row >> 3) & 7))];
    }

    // ---- exact numpy sums, 8 lanes per row, coalesced global loads ----
    // lane m owns accumulator r[m] (elements m, m+8, ..., m+56, in order);
    // shfl_xor 1/2/4 tree = ((r0+r1)+(r2+r3))+((r4+r5)+(r6+r7)) exactly.
    {
#pragma clang fp contract(off)
#pragma unroll 1
        for (int rnd = 0; rnd < (ROWS * 8) / BLOCK; ++rnd) {     // 4 rounds
            int slot = tid + rnd * BLOCK;
            int r = slot >> 3, m = slot & 7;
            const float* xp = x + (size_t)(rowbase + r) * D + m;
            float v = xp[0];
            float rm = v * v;
#pragma unroll
            for (int t = 1; t < 8; ++t) {
                v = xp[8 * t];
                rm = rm + v * v;
            }
            float o;
            o = __shfl_xor(rm, 1, 64); rm = rm + o;
            o = __shfl_xor(rm, 2, 64); rm = rm + o;
            o = __shfl_xor(rm, 4, 64); rm = rm + o;
            if (m == 0) sx_s[r] = rm;
        }
#pragma unroll 1
        for (int rnd = 0; rnd < (K * 8) / BLOCK; ++rnd) {        // 16 rounds
            int slot = tid + rnd * BLOCK;
            int r = slot >> 3, m = slot & 7;
            const float* ep = emb + (size_t)r * D + m;
            float v = ep[0];
            float rm = v * v;
#pragma unroll
            for (int t = 1; t < 8; ++t) {
                v = ep[8 * t];
                rm = rm + v * v;
            }
            float o;
            o = __shfl_xor(rm, 1, 64); rm = rm + o;
            o = __shfl_xor(rm, 2, 64); rm = rm + o;
            o = __shfl_xor(rm, 4, 64); rm = rm + o;
            if (m == 0) se_s[r] = rm;
        }
    }
    __syncthreads();

    float bd[8], bkf[8];
#pragma unroll
    for (int r = 0; r < 8; ++r) { bd[r] = INFINITY; bkf[r] = 0.f; }

    const int xbase = rg * 8, ebase = cg * 8;
    const int swx0 = rg & 7, swe0 = cg & 7;

#pragma unroll 1
    for (int kt = 0; kt < NKT; ++kt) {
        // ---- stage e tile: pre-swizzled global read, linear LDS store ----
        const float4* esrc = (const float4*)(emb + (size_t)kt * KT * D);
#pragma unroll
        for (int i = 0; i < (KT * 16) / BLOCK; ++i) {
            int f = tid + i * BLOCK;
            int row = f >> 4, s = f & 15;
            es4[f] = esrc[row * 16 + (s ^ ((row >> 3) & 7))];
        }
        __syncthreads();

        float acc[8][8];
#pragma unroll
        for (int r = 0; r < 8; ++r)
#pragma unroll
            for (int c = 0; c < 8; ++c) acc[r][c] = 0.f;

        // 16:1 FMA:DS inner loop; each acc is a sequential ascending-j chain
#pragma unroll 2
        for (int jc = 0; jc < 16; ++jc) {
            float4 xa[8], eb[8];
#pragma unroll
            for (int r = 0; r < 8; ++r)
                xa[r] = xs4[(xbase + r) * 16 + (jc ^ swx0)];
#pragma unroll
            for (int c = 0; c < 8; ++c)
                eb[c] = es4[(ebase + c) * 16 + (jc ^ swe0)];
#pragma unroll
            for (int r = 0; r < 8; ++r)
#pragma unroll
                for (int c = 0; c < 8; ++c) {
                    acc[r][c] = fmaf(xa[r].x, eb[c].x, acc[r][c]);
                    acc[r][c] = fmaf(xa[r].y, eb[c].y, acc[r][c]);
                    acc[r][c] = fmaf(xa[r].z, eb[c].z, acc[r][c]);
                    acc[r][c] = fmaf(xa[r].w, eb[c].w, acc[r][c]);
                }
        }
        __syncthreads();    // all es4 reads done

        // dist + running first-min (kt ascending, c ascending, strict <)
        const int kglob = kt * KT + ebase;
        float sev[8];
#pragma unroll
        for (int c = 0; c < 8; ++c) sev[c] = se_s[kglob + c];
#pragma unroll
        for (int r = 0; r < 8; ++r) {
            float sxv = sx_s[xbase + r];
#pragma unroll
            for (int c = 0; c < 8; ++c) {
                float dcur = (sxv + sev[c]) - 2.0f * acc[r][c];  // ref rounding
                if (dcur < bd[r]) { bd[r] = dcur; bkf[r] = (float)(kglob + c); }
            }
        }
    }

    // ---- cross-thread argmin: lexicographic (d, k) over 16 code-groups ----
    float2* bests = (float2*)es4;   // alias; 128*17*8B = 17.4 KB < 32 KB
#pragma unroll
    for (int r = 0; r < 8; ++r)
        bests[(xbase + r) * BSTRIDE + cg] = make_float2(bd[r], bkf[r]);
    __syncthreads();

    float s = 0.f;
    if (tid < ROWS) {
        float bdd = INFINITY, bjf = 1e30f;
#pragma unroll
        for (int g = 0; g < 16; ++g) {
            float2 p = bests[tid * BSTRIDE + g];
            if (p.x < bdd || (p.x == bdd && p.y < bjf)) { bdd = p.x; bjf = p.y; }
        }
        const int bi = (int)bjf;
        atomicAdd(&hist[bi], 1);

        const int rowg = rowbase + tid;
        const float4* ep = (const float4*)(emb + (size_t)bi * D);
        float4* qp = (float4*)(q_out + (size_t)rowg * D);
        const int sw = (tid >> 3) & 7;
#pragma unroll
        for (int jc = 0; jc < 16; ++jc) {
            float4 xv = xs4[tid * 16 + (jc ^ sw)];   // bit-identical x copy
            float4 e  = ep[jc];
            float dx0 = e.x - xv.x, dx1 = e.y - xv.y;
            float dx2 = e.z - xv.z, dx3 = e.w - xv.w;
            s = fmaf(dx0, dx0, s);
            s = fmaf(dx1, dx1, s);
            s = fmaf(dx2, dx2, s);
            s = fmaf(dx3, dx3, s);
            float4 qs;  // straight-through: x + (q - x)
            qs.x = xv.x + dx0; qs.y = xv.y + dx1;
            qs.z = xv.z + dx2; qs.w = xv.w + dx3;
            qp[jc] = qs;
        }
        idx_out[rowg] = (float)bi;
    }

    // ---- loss partial (inactive waves contribute 0) ----
    for (int off = 32; off; off >>= 1) s += __shfl_down(s, off, 64);
    if (lane == 0) redf[wv] = s;
    __syncthreads();            // also orders hist atomics before flush
    if (tid == 0) {
        float t = 0.f;
#pragma unroll
        for (int w = 0; w < BLOCK / 64; ++w) t += redf[w];
        block_sums[blockIdx.x] = t;
    }
    // per-block hist -> one of 32 partial hists (skip zeros)
    const int part = (int)(blockIdx.x & (NPART - 1));
    for (int k2 = tid; k2 < K; k2 += BLOCK) {
        int h = hist[k2];
        if (h) atomicAdd(&part_hist[part * K + k2], h);
    }
}

__global__ __launch_bounds__(512) void vq_finalize(
    const float* __restrict__ block_sums, int nblocks,
    const int* __restrict__ part_hist, float* __restrict__ out_loss,
    float* __restrict__ out_perp, float inv_nelem, float inv_rows)
{
    const int tid = threadIdx.x;
    double ls = 0.0;
    for (int i = tid; i < nblocks; i += 512) ls += (double)block_sums[i];
    int c = 0;
#pragma unroll
    for (int pp = 0; pp < NPART; ++pp) c += part_hist[pp * K + tid];  // coalesced
    double ps = 0.0;
    {
        float p = (float)c * inv_rows;          // tid < 512 == K
        ps = (double)(p * logf(p + 1e-10f));
    }
    for (int off = 32; off; off >>= 1) {
        ls += __shfl_down(ls, off, 64);
        ps += __shfl_down(ps, off, 64);
    }
    __shared__ double l8[8], p8[8];
    if ((tid & 63) == 0) { l8[tid >> 6] = ls; p8[tid >> 6] = ps; }
    __syncthreads();
    if (tid == 0) {
        double L = 0.0, P = 0.0;
#pragma unroll
        for (int w = 0; w < 8; ++w) { L += l8[w]; P += p8[w]; }
        // loss = q_latent + 0.25*e_latent; forward values identical
        *out_loss = 1.25f * (float)(L * (double)inv_nelem);
        *out_perp = expf((float)(-P));
    }
}

extern "C" void kernel_launch(void* const* d_in, const int* in_sizes, int n_in,
                              void* d_out, int out_size, void* d_ws, size_t ws_size,
                              hipStream_t stream) {
    const float* x   = (const float*)d_in[0];
    const float* emb = (const float*)d_in[1];
    const int N = in_sizes[0] / D;          // 65536 rows
    const int nblocks = N / ROWS;           // 512

    float* out      = (float*)d_out;
    float* loss_out = out;                  // [0]
    float* q_out    = out + 1;              // [1 .. N*D]
    float* perp_out = out + 1 + (size_t)N * D;
    float* idx_out  = perp_out + 1;         // [.. + N]

    // ws: [block_sums: nblocks f32 | pad 256B][part_hist: 32*512 i32]
    float* block_sums = (float*)d_ws;
    int*   part_hist  = (int*)((char*)d_ws +
                               (((size_t)nblocks * 4 + 255) & ~(size_t)255));

    hipMemsetAsync(part_hist, 0, (size_t)NPART * K * sizeof(int), stream);
    vq_fused<<<nblocks, BLOCK, 0, stream>>>(x, emb, q_out, idx_out,
                                            block_sums, part_hist, N);
    vq_finalize<<<1, 512, 0, stream>>>(block_sums, nblocks, part_hist,
                                       loss_out, perp_out,
                                       1.0f / (float)((size_t)N * D),
                                       1.0f / (float)N);
}